// Round 16
// baseline (262.304 us; speedup 1.0000x reference)
//
#include <hip/hip_runtime.h>
#include <hip/hip_bf16.h>
#include <stdint.h>
#include <stddef.h>

// E=8, B=16, T=512, DIN=256, D=256; M = B*T = 8192 rows per ensemble member.
// Stage1: u = x @ W_in[m], v=tanh(u0), f=sig(u1)*(1-rs)  -> scan1 -> v4
// Stage2: u = v4 @ W_mid[m], gates f,i,o,z               -> scan2 -> g = h*o
// Stage3: out = g @ W_out + b_out
//
// r16: gemm2/gemm3 rebuilt BARRIER-FREE and LDS-FREE: each wave is an
// independent worker (64 rows x 32 cols per tile), B in registers, A read
// directly from global (L2-resident, e-pinned XCD), scan fully in-wave
// (in-lane 4 + 16-lane DPP scan + ds_bpermute lane15 broadcast, h in
// registers across the 8-tile sequence chain). No s_barrier / waitcnt in
// the main loop -> waves drift and fill each other's stalls.
// gemm1 keeps r15's proven f32-reg-staged LDS path.

typedef __bf16 bf16x8 __attribute__((ext_vector_type(8)));
typedef __bf16 bf16x4 __attribute__((ext_vector_type(4)));
typedef __bf16 bf16x2 __attribute__((ext_vector_type(2)));
typedef float  f32x4  __attribute__((ext_vector_type(4)));
typedef float  f32x2  __attribute__((ext_vector_type(2)));

#define E_ 8
#define M_ 8192
#define K_ 256

__device__ __forceinline__ float sigm_f(float x) {
    return __builtin_amdgcn_rcpf(1.0f + __expf(-x));
}
__device__ __forceinline__ float tanh_f(float x) {
    return 1.0f - 2.0f * __builtin_amdgcn_rcpf(1.0f + __expf(2.0f * x));
}

__device__ __forceinline__ void g2lds16(const void* g, void* l) {
    __builtin_amdgcn_global_load_lds((const __attribute__((address_space(1))) void*)g,
                                     (__attribute__((address_space(3))) void*)l, 16, 0, 0);
}

// DPP row_shr with 0-fill (bound_ctrl=1); rows of 16 lanes = our ln15 groups.
template <int D>
__device__ __forceinline__ float dppshr(float x) {
    return __builtin_bit_cast(float,
        __builtin_amdgcn_update_dpp(0, __builtin_bit_cast(int, x),
                                    0x110 | D, 0xF, 0xF, true));
}

// Inclusive Hillis scan of (A,B) over 16-lane rows, then exclusive prefix.
__device__ __forceinline__ void lane_scan(float& A, float& B, float& EA, float& EB, int ln15) {
    float As, Bs;
    Bs = dppshr<1>(B); As = dppshr<1>(A); B = __builtin_fmaf(A, Bs, B); A = (ln15 >= 1) ? A * As : A;
    Bs = dppshr<2>(B); As = dppshr<2>(A); B = __builtin_fmaf(A, Bs, B); A = (ln15 >= 2) ? A * As : A;
    Bs = dppshr<4>(B); As = dppshr<4>(A); B = __builtin_fmaf(A, Bs, B); A = (ln15 >= 4) ? A * As : A;
    Bs = dppshr<8>(B); As = dppshr<8>(A); B = __builtin_fmaf(A, Bs, B); A = (ln15 >= 8) ? A * As : A;
    EA = dppshr<1>(A); EA = (ln15 >= 1) ? EA : 1.0f;
    EB = dppshr<1>(B);
}

// ---------------- merged transpose+convert for all three weight sets ----------------
__global__ __launch_bounds__(256) void transw_all(const float* __restrict__ W_in,
                                                  const float* __restrict__ W_mid,
                                                  const float* __restrict__ W_out,
                                                  __bf16* __restrict__ Wt1,
                                                  __bf16* __restrict__ Wt2,
                                                  __bf16* __restrict__ Wt3) {
    int z = blockIdx.z;
    const float* src; __bf16* dst; int NG, ilv, ge;
    if (z < 16)      { src = W_in;  dst = Wt1; NG = 2; ilv = 1; ge = z; }
    else if (z < 48) { src = W_mid; dst = Wt2; NG = 4; ilv = 1; ge = z - 16; }
    else             { src = W_out; dst = Wt3; NG = 1; ilv = 0; ge = z - 48; }
    int g = ge >> 3, e = ge & 7;
    int k0 = blockIdx.x * 64, d0 = blockIdx.y * 64;
    __shared__ float tile[64][65];
    int t = threadIdx.x;
#pragma unroll
    for (int j = 0; j < 16; ++j) {
        int lin = j * 256 + t;
        int r = lin >> 6, c = lin & 63;
        tile[r][c] = src[((size_t)(ge * 256 + k0 + r)) * 256 + d0 + c];
    }
    __syncthreads();
#pragma unroll
    for (int j = 0; j < 16; ++j) {
        int lin = j * 256 + t;
        int r = lin >> 6, c = lin & 63;     // r = d offset, c = k offset
        int d = d0 + r;
        int row = ilv ? (d * NG + g) : (g * 256 + d);
        dst[((size_t)(e * NG * 256 + row)) * K_ + k0 + c] = (__bf16)tile[c][r];
    }
}

// ---------------- gemm1: r15 MODE0 (f32 reg-staged, fused scan1, deferred epi) ----------------
__global__ __launch_bounds__(512, 1) void gemm1_k(const float* __restrict__ Af,
                                                  const __bf16* __restrict__ Wt,
                                                  const float* __restrict__ bias,
                                                  const float* __restrict__ rs,
                                                  __bf16* __restrict__ gout,
                                                  const float* __restrict__ hidden,
                                                  float* __restrict__ hidout) {
    constexpr int NT  = 4;               // n-panels of 128 over 512 cols
    constexpr int NMT = 8;
    const int tid = threadIdx.x;
    const int bid = blockIdx.x;
    const int e  = bid & 7;
    const int rr = bid >> 3;
    const int nt = rr & (NT - 1);
    const int ms = rr / NT;
    const int mt0 = ms * NMT;
    const int lane = tid & 63, wid = tid >> 6;
    const int wr = wid >> 2, wc = wid & 3;
    const int ln15 = lane & 15, ln16 = lane >> 4;

    __shared__ __align__(16) __bf16 As[2][32768];
    __shared__ float cAl[64], cBl[64];
    __shared__ float chL[2][64];

    bf16x8 Breg[2][8];
    {
        const __bf16* bp = Wt + ((size_t)e * 512 + nt * 128 + wc * 32 + ln15) * K_ + ln16 * 8;
#pragma unroll
        for (int j = 0; j < 2; ++j)
#pragma unroll
            for (int s = 0; s < 8; ++s)
                Breg[j][s] = *(const bf16x8*)(bp + (size_t)j * 16 * K_ + s * 32);
    }
    f32x4 bias_v[2];
#pragma unroll
    for (int j = 0; j < 2; ++j)
#pragma unroll
        for (int q = 0; q < 4; ++q) {
            int n = nt * 128 + wc * 32 + j * 16 + (ln16 << 2) + q;
            bias_v[j][q] = bias[((n & 1) * E_ + e) * 256 + (n >> 1)];
        }

    const int sr = tid >> 5, sr2 = sr >> 2;
    const int gg0 = (tid & 31) ^ sr2;
    const size_t Aoff = ((size_t)e * M_ + (size_t)mt0 * 128) * K_;
    const float* sEf = Af + Aoff + (size_t)sr * K_ + gg0 * 8;
    const float* sOf = Af + Aoff + (size_t)sr * K_ + (gg0 ^ 4) * 8;
    __bf16* const dbase0 = &As[0][tid * 8];
    __bf16* const dbase1 = &As[1][tid * 8];

    f32x4 tA[8], tB[8];
    auto loadx = [&](int tt) {
        const size_t toff = (size_t)tt * (128 * K_);
#pragma unroll
        for (int q = 0; q < 8; ++q) {
            const float* s = ((q & 1) ? sOf : sEf) + toff + q * (16 * K_);
            tA[q] = *(const f32x4*)s;
            tB[q] = *(const f32x4*)(s + 4);
        }
    };
    auto writex = [&](int buf) {
        __bf16* d = buf ? dbase1 : dbase0;
#pragma unroll
        for (int q = 0; q < 8; ++q) {
            bf16x8 w;
#pragma unroll
            for (int k = 0; k < 4; ++k) { w[k] = (__bf16)tA[q][k]; w[4 + k] = (__bf16)tB[q][k]; }
            *(bf16x8*)(d + q * 4096) = w;
        }
    };

    const int rowb = (wr * 64 + ln15 * 4) * K_;
    const int gb = ln16 ^ (lane & 7);
    const int pe_off = rowb + gb * 8;
    const int po_off = rowb + (gb ^ 4) * 8;

    auto compute = [&](f32x4 (&acc)[4][2], int buf) {
        const __bf16* pe = &As[0][0] + buf * 32768 + pe_off;
        const __bf16* po = &As[0][0] + buf * 32768 + po_off;
#pragma unroll
        for (int s = 0; s < 8; ++s) {
            const __bf16* p = (s & 1) ? po : pe;
            bf16x8 af[4];
#pragma unroll
            for (int i = 0; i < 4; ++i)
                af[i] = *(const bf16x8*)(p + i * K_ + (s >> 1) * 64);
#pragma unroll
            for (int i = 0; i < 4; ++i)
#pragma unroll
                for (int j = 0; j < 2; ++j)
                    acc[i][j] = __builtin_amdgcn_mfma_f32_16x16x32_bf16(Breg[j][s], af[i], acc[i][j], 0, 0, 0);
        }
    };

    auto do_epi = [&](f32x4 (&acc)[4][2], int tp, const f32x4& rs4p, const float* hidvp) {
        const bool cs = ((tp & 3) == 0);
        const int c = tp >> 2;
        const int mb = (mt0 + tp) * 128 + wr * 64 + ln15 * 4;
        f32x4 rsv;
#pragma unroll
        for (int q = 0; q < 4; ++q) rsv[q] = 1.0f - rs4p[q];
        float PA[2][2][4], PB[2][2][4], LA[2][2], LB[2][2], EA[2][2], EB[2][2];
#pragma unroll
        for (int j = 0; j < 2; ++j) {
#pragma unroll
            for (int dq = 0; dq < 2; ++dq) {
#pragma unroll
                for (int i = 0; i < 4; ++i) {
                    float uv = acc[i][j][dq * 2 + 0] + bias_v[j][dq * 2 + 0];
                    float uf = acc[i][j][dq * 2 + 1] + bias_v[j][dq * 2 + 1];
                    float f = sigm_f(uf) * rsv[i];
                    float b = (1.0f - f) * tanh_f(uv);
                    if (i == 0) { PA[j][dq][0] = f; PB[j][dq][0] = b; }
                    else { PB[j][dq][i] = __builtin_fmaf(f, PB[j][dq][i - 1], b);
                           PA[j][dq][i] = PA[j][dq][i - 1] * f; }
                }
                LA[j][dq] = PA[j][dq][3]; LB[j][dq] = PB[j][dq][3];
                lane_scan(LA[j][dq], LB[j][dq], EA[j][dq], EB[j][dq], ln15);
            }
#pragma unroll
            for (int i = 0; i < 4; ++i) acc[i][j] = f32x4{};
        }
        if (wr == 0 && ln15 == 15) {
#pragma unroll
            for (int j = 0; j < 2; ++j)
#pragma unroll
                for (int dq = 0; dq < 2; ++dq) {
                    int sl = wc * 16 + j * 8 + ln16 * 2 + dq;
                    cAl[sl] = LA[j][dq]; cBl[sl] = LB[j][dq];
                }
        }
        asm volatile("s_waitcnt lgkmcnt(0)" ::: "memory");
        __builtin_amdgcn_s_barrier();
#pragma unroll
        for (int j = 0; j < 2; ++j) {
            const int D0 = nt * 64 + wc * 16 + j * 8 + ln16 * 2;
            float h0q[2];
#pragma unroll
            for (int dq = 0; dq < 2; ++dq) {
                const int sl = wc * 16 + j * 8 + ln16 * 2 + dq;
                float hp = cs ? hidvp[j * 2 + dq] : chL[tp & 1][sl];
                float hsv = wr ? __builtin_fmaf(cAl[sl], hp, cBl[sl]) : hp;
                h0q[dq] = __builtin_fmaf(EA[j][dq], hsv, EB[j][dq]);
                if (wr == 1 && ln15 == 15) {
                    float he = __builtin_fmaf(LA[j][dq], hsv, LB[j][dq]);
                    chL[(tp + 1) & 1][sl] = he;
                    if ((tp & 3) == 3)
                        hidout[(e * 16 + ms * 2 + c) * 512 + D0 + dq] = he;
                }
            }
#pragma unroll
            for (int i = 0; i < 4; ++i) {
                float ha = __builtin_fmaf(PA[j][0][i], h0q[0], PB[j][0][i]);
                float hb = __builtin_fmaf(PA[j][1][i], h0q[1], PB[j][1][i]);
                bf16x2 pk; pk[0] = (__bf16)ha; pk[1] = (__bf16)hb;
                *(unsigned int*)&gout[((size_t)e * M_ + mb + i) * 256 + D0] =
                    __builtin_bit_cast(unsigned int, pk);
            }
        }
    };

    // prologue
    loadx(0);
    asm volatile("s_waitcnt vmcnt(0)" ::: "memory");
    writex(0);
    asm volatile("s_waitcnt lgkmcnt(0)" ::: "memory");
    __builtin_amdgcn_s_barrier();
    __builtin_amdgcn_sched_barrier(0);

    f32x4 accA[4][2] = {}, accB[4][2] = {};
    f32x4 rs4_p = {};
    float hidv_p[4] = {0.f, 0.f, 0.f, 0.f};
    int buf = 0;

    auto iter = [&](int t, f32x4 (&accC)[4][2], f32x4 (&accP)[4][2]) {
        const int c = t >> 2;
        f32x4 rs4_n;
        float hidv_n[4];
        {
            const int mbh = (mt0 + t) * 128 + wr * 64 + ln15 * 4;
            rs4_n = *(const f32x4*)&rs[mbh];
            const int nrow = e * 16 + ms * 2 + c;
            f32x2 ha = *(const f32x2*)&hidden[nrow * 512 + (nt * 64 + wc * 16 + 0 + ln16 * 2)];
            f32x2 hb = *(const f32x2*)&hidden[nrow * 512 + (nt * 64 + wc * 16 + 8 + ln16 * 2)];
            hidv_n[0] = ha[0]; hidv_n[1] = ha[1]; hidv_n[2] = hb[0]; hidv_n[3] = hb[1];
            __builtin_amdgcn_sched_barrier(0);
        }
        if (t + 1 < NMT) loadx(t + 1);
        __builtin_amdgcn_sched_barrier(0);
        compute(accC, buf);
        if (t > 0) do_epi(accP, t - 1, rs4_p, hidv_p);
        if (t == 0) { asm volatile("s_waitcnt vmcnt(0)" ::: "memory"); }
        else        { asm volatile("s_waitcnt vmcnt(8)" ::: "memory"); }
        if (t + 1 < NMT) writex(buf ^ 1);
        asm volatile("s_waitcnt lgkmcnt(0)" ::: "memory");
        __builtin_amdgcn_s_barrier();
        __builtin_amdgcn_sched_barrier(0);
        buf ^= 1;
        rs4_p = rs4_n;
#pragma unroll
        for (int q = 0; q < 4; ++q) hidv_p[q] = hidv_n[q];
    };

#pragma unroll 1
    for (int t2 = 0; t2 < NMT; t2 += 2) {
        iter(t2, accA, accB);
        iter(t2 + 1, accB, accA);
    }
    do_epi(accB, NMT - 1, rs4_p, hidv_p);
}

// ---------------- gemm2: barrier-free wave-worker, fused scan2 ----------------
// Wave = (e, cg 0..31, b 0..15): 32 output cols (interleaved d*4+g), one
// sequence chain of 8 tiles x 64 rows. A read direct from global.
__global__ __launch_bounds__(256) void gemm2_k(const __bf16* __restrict__ A,
                                               const __bf16* __restrict__ Wt,
                                               const float* __restrict__ bias,
                                               const float* __restrict__ rs,
                                               __bf16* __restrict__ G,
                                               const float* __restrict__ hidden,
                                               float* __restrict__ hidout) {
    const int tid = threadIdx.x;
    const int lane = tid & 63, wid = tid >> 6;
    const int bid = blockIdx.x;            // 1024
    const int e = bid & 7;
    const int wk = (bid >> 3) * 4 + wid;   // 0..511
    const int cg = wk >> 4;                // 0..31
    const int b  = wk & 15;                // 0..15
    const int ln15 = lane & 15, ln16 = lane >> 4;

    bf16x8 Breg[2][8];
    {
        const __bf16* bp = Wt + ((size_t)e * 1024 + cg * 32 + ln15) * K_ + ln16 * 8;
#pragma unroll
        for (int j = 0; j < 2; ++j)
#pragma unroll
            for (int s = 0; s < 8; ++s)
                Breg[j][s] = *(const bf16x8*)(bp + (size_t)j * 16 * K_ + s * 32);
    }
    f32x4 bias_v[2];
#pragma unroll
    for (int j = 0; j < 2; ++j)
#pragma unroll
        for (int q = 0; q < 4; ++q) {
            int n = cg * 32 + j * 16 + (ln16 << 2) + q;
            bias_v[j][q] = bias[((n & 3) * E_ + e) * 256 + (n >> 2)];
        }

    const size_t Ab = ((size_t)e * M_ + (size_t)b * 512) * K_;
    const __bf16* ap = A + Ab + (size_t)(ln15 * 4) * K_ + ln16 * 8;
    const int d0 = cg * 8 + ln16;          // j=0 d; j=1 -> +4
    float hs[2];
    hs[0] = hidden[(e * 16 + b) * 512 + 256 + d0];
    hs[1] = hidden[(e * 16 + b) * 512 + 256 + d0 + 4];
    const int bpa = (lane | 15) << 2;

#pragma unroll 1
    for (int t = 0; t < 8; ++t) {
        const int mb = b * 512 + t * 64 + ln15 * 4;
        f32x4 rs4 = *(const f32x4*)&rs[mb];
        const __bf16* at = ap + (size_t)t * (64 * K_);
        f32x4 acc[4][2] = {};
#pragma unroll
        for (int s = 0; s < 8; ++s) {
            bf16x8 af[4];
#pragma unroll
            for (int i = 0; i < 4; ++i)
                af[i] = *(const bf16x8*)(at + i * K_ + s * 32);
#pragma unroll
            for (int i = 0; i < 4; ++i) {
                acc[i][0] = __builtin_amdgcn_mfma_f32_16x16x32_bf16(Breg[0][s], af[i], acc[i][0], 0, 0, 0);
                acc[i][1] = __builtin_amdgcn_mfma_f32_16x16x32_bf16(Breg[1][s], af[i], acc[i][1], 0, 0, 0);
            }
        }
        f32x4 rsv;
#pragma unroll
        for (int q = 0; q < 4; ++q) rsv[q] = 1.0f - rs4[q];
#pragma unroll
        for (int j = 0; j < 2; ++j) {
            float PA[4], PB[4], Ov[4];
#pragma unroll
            for (int i = 0; i < 4; ++i) {
                float f  = sigm_f(acc[i][j][0] + bias_v[j][0]) * rsv[i];
                float iv = sigm_f(acc[i][j][1] + bias_v[j][1]);
                float o  = sigm_f(acc[i][j][2] + bias_v[j][2]);
                float z  = tanh_f(acc[i][j][3] + bias_v[j][3]);
                float bb = (1.0f - f) * iv * z;
                Ov[i] = o;
                PA[i] = i ? PA[i - 1] * f : f;
                PB[i] = i ? __builtin_fmaf(f, PB[i - 1], bb) : bb;
            }
            float LA = PA[3], LB = PB[3], EA, EB;
            lane_scan(LA, LB, EA, EB, ln15);
            float h0 = __builtin_fmaf(EA, hs[j], EB);
            const int d = d0 + j * 4;
#pragma unroll
            for (int i = 0; i < 4; ++i) {
                float h = __builtin_fmaf(PA[i], h0, PB[i]);
                G[((size_t)e * M_ + mb + i) * 256 + d] = (__bf16)(h * Ov[i]);
            }
            float hn = __builtin_fmaf(LA, hs[j], LB);
            hn = __builtin_bit_cast(float,
                 __builtin_amdgcn_ds_bpermute(bpa, __builtin_bit_cast(int, hn)));
            hs[j] = hn;
            if (t == 7 && ln15 == 15)
                hidout[(e * 16 + b) * 512 + 256 + d] = hn;
        }
    }
}

// ---------------- gemm3: barrier-free wave-worker, plain linear+bias ----------------
// Wave = (e, cg 0..7, mt 0..127): 32 cols x 64 rows, f32x4 stores.
__global__ __launch_bounds__(256) void gemm3_k(const __bf16* __restrict__ A,
                                               const __bf16* __restrict__ Wt,
                                               const float* __restrict__ bias,
                                               float* __restrict__ out) {
    const int tid = threadIdx.x;
    const int lane = tid & 63, wid = tid >> 6;
    const int bid = blockIdx.x;            // 2048
    const int e = bid & 7;
    const int wk = (bid >> 3) * 4 + wid;   // 0..1023
    const int cg = wk >> 7;                // 0..7
    const int mt = wk & 127;               // 0..127
    const int ln15 = lane & 15, ln16 = lane >> 4;

    bf16x8 Breg[2][8];
    {
        const __bf16* bp = Wt + ((size_t)e * 256 + cg * 32 + ln15) * K_ + ln16 * 8;
#pragma unroll
        for (int j = 0; j < 2; ++j)
#pragma unroll
            for (int s = 0; s < 8; ++s)
                Breg[j][s] = *(const bf16x8*)(bp + (size_t)j * 16 * K_ + s * 32);
    }
    f32x4 bias_v[2];
#pragma unroll
    for (int j = 0; j < 2; ++j)
        bias_v[j] = *(const f32x4*)&bias[e * 256 + cg * 32 + j * 16 + (ln16 << 2)];

    const __bf16* at = A + ((size_t)e * M_ + mt * 64 + ln15 * 4) * K_ + ln16 * 8;
    f32x4 acc[4][2] = {};
#pragma unroll
    for (int s = 0; s < 8; ++s) {
        bf16x8 af[4];
#pragma unroll
        for (int i = 0; i < 4; ++i)
            af[i] = *(const bf16x8*)(at + i * K_ + s * 32);
#pragma unroll
        for (int i = 0; i < 4; ++i) {
            acc[i][0] = __builtin_amdgcn_mfma_f32_16x16x32_bf16(Breg[0][s], af[i], acc[i][0], 0, 0, 0);
            acc[i][1] = __builtin_amdgcn_mfma_f32_16x16x32_bf16(Breg[1][s], af[i], acc[i][1], 0, 0, 0);
        }
    }
    const int mb = mt * 64 + ln15 * 4;
#pragma unroll
    for (int j = 0; j < 2; ++j) {
        const int n0 = cg * 32 + j * 16 + (ln16 << 2);
#pragma unroll
        for (int i = 0; i < 4; ++i) {
            f32x4 o = acc[i][j] + bias_v[j];
            *(f32x4*)&out[((size_t)e * M_ + mb + i) * 256 + n0] = o;
        }
    }
}

extern "C" void kernel_launch(void* const* d_in, const int* in_sizes, int n_in,
                              void* d_out, int out_size, void* d_ws, size_t ws_size,
                              hipStream_t stream) {
    const float* x      = (const float*)d_in[0];
    const float* hidden = (const float*)d_in[1];
    const float* rs     = (const float*)d_in[2];
    const float* W_in   = (const float*)d_in[3];
    const float* b_in   = (const float*)d_in[4];
    const float* W_mid  = (const float*)d_in[5];
    const float* b_mid  = (const float*)d_in[6];
    const float* W_out  = (const float*)d_in[7];
    const float* b_out  = (const float*)d_in[8];
    float* out = (float*)d_out;

    char* ws = (char*)d_ws;
    const size_t MiB = (size_t)1 << 20;
    __bf16* Wt1 = (__bf16*)(ws + 0);               // 2 MiB  (ilv d*2+g)
    __bf16* Wt2 = (__bf16*)(ws + 2 * MiB);         // 4 MiB  (ilv d*4+g)
    __bf16* Wt3 = (__bf16*)(ws + 6 * MiB);         // 1 MiB  (plain)
    __bf16* v4b = (__bf16*)(ws + 8 * MiB);         // 32 MiB scan1 output
    __bf16* G   = (__bf16*)(ws + 72 * MiB);        // 32 MiB scan2 output

    float* hidout = out + (size_t)E_ * M_ * 256;

    transw_all<<<dim3(4, 4, 56), 256, 0, stream>>>(W_in, W_mid, W_out, Wt1, Wt2, Wt3);

    gemm1_k<<<256, 512, 0, stream>>>(x, Wt1, b_in, rs, v4b, hidden, hidout);
    gemm2_k<<<1024, 256, 0, stream>>>(v4b, Wt2, b_mid, rs, G, hidden, hidout);
    gemm3_k<<<2048, 256, 0, stream>>>(G, Wt3, b_out, out);
}

// Round 17
// 239.663 us; speedup vs baseline: 1.0945x; 1.0945x over previous
//
#include <hip/hip_runtime.h>
#include <hip/hip_bf16.h>
#include <stdint.h>
#include <stddef.h>

// E=8, B=16, T=512, DIN=256, D=256; M = B*T = 8192 rows per ensemble member.
// Stage1: u = x @ W_in[m], v=tanh(u0), f=sig(u1)*(1-rs)  -> scan1 -> v4
// Stage2: u = v4 @ W_mid[m], gates f,i,o,z               -> scan2 -> g = h*o
// Stage3: out = g @ W_out + b_out
//
// r17 = r15 (best passing, 162.3us) with gemm2 rebuilt for 2 blocks/CU:
// BK=128 chunk-parity LDS double-buffer (64KB), grid 512, launch_bounds(512,4),
// deferred epilogue retained. Same MFMA accumulation order and epilogue math
// as r15 -> bit-identical numerics. gemm1 (f32-reg-staged) and gemm3 unchanged.

typedef __bf16 bf16x8 __attribute__((ext_vector_type(8)));
typedef __bf16 bf16x4 __attribute__((ext_vector_type(4)));
typedef __bf16 bf16x2 __attribute__((ext_vector_type(2)));
typedef float  f32x4  __attribute__((ext_vector_type(4)));
typedef float  f32x2  __attribute__((ext_vector_type(2)));

#define E_ 8
#define M_ 8192
#define K_ 256

__device__ __forceinline__ float sigm_f(float x) {
    return __builtin_amdgcn_rcpf(1.0f + __expf(-x));
}
__device__ __forceinline__ float tanh_f(float x) {
    return 1.0f - 2.0f * __builtin_amdgcn_rcpf(1.0f + __expf(2.0f * x));
}

__device__ __forceinline__ void g2lds16(const void* g, void* l) {
    __builtin_amdgcn_global_load_lds((const __attribute__((address_space(1))) void*)g,
                                     (__attribute__((address_space(3))) void*)l, 16, 0, 0);
}

// DPP row_shr with 0-fill (bound_ctrl=1); rows of 16 lanes = our ln15 groups.
template <int D>
__device__ __forceinline__ float dppshr(float x) {
    return __builtin_bit_cast(float,
        __builtin_amdgcn_update_dpp(0, __builtin_bit_cast(int, x),
                                    0x110 | D, 0xF, 0xF, true));
}

// Inclusive Hillis scan of (A,B) over 16-lane rows, then exclusive prefix.
__device__ __forceinline__ void lane_scan(float& A, float& B, float& EA, float& EB, int ln15) {
    float As, Bs;
    Bs = dppshr<1>(B); As = dppshr<1>(A); B = __builtin_fmaf(A, Bs, B); A = (ln15 >= 1) ? A * As : A;
    Bs = dppshr<2>(B); As = dppshr<2>(A); B = __builtin_fmaf(A, Bs, B); A = (ln15 >= 2) ? A * As : A;
    Bs = dppshr<4>(B); As = dppshr<4>(A); B = __builtin_fmaf(A, Bs, B); A = (ln15 >= 4) ? A * As : A;
    Bs = dppshr<8>(B); As = dppshr<8>(A); B = __builtin_fmaf(A, Bs, B); A = (ln15 >= 8) ? A * As : A;
    EA = dppshr<1>(A); EA = (ln15 >= 1) ? EA : 1.0f;
    EB = dppshr<1>(B);
}

// ---------------- merged transpose+convert for all three weight sets ----------------
__global__ __launch_bounds__(256) void transw_all(const float* __restrict__ W_in,
                                                  const float* __restrict__ W_mid,
                                                  const float* __restrict__ W_out,
                                                  __bf16* __restrict__ Wt1,
                                                  __bf16* __restrict__ Wt2,
                                                  __bf16* __restrict__ Wt3) {
    int z = blockIdx.z;
    const float* src; __bf16* dst; int NG, ilv, ge;
    if (z < 16)      { src = W_in;  dst = Wt1; NG = 2; ilv = 1; ge = z; }
    else if (z < 48) { src = W_mid; dst = Wt2; NG = 4; ilv = 1; ge = z - 16; }
    else             { src = W_out; dst = Wt3; NG = 1; ilv = 0; ge = z - 48; }
    int g = ge >> 3, e = ge & 7;
    int k0 = blockIdx.x * 64, d0 = blockIdx.y * 64;
    __shared__ float tile[64][65];
    int t = threadIdx.x;
#pragma unroll
    for (int j = 0; j < 16; ++j) {
        int lin = j * 256 + t;
        int r = lin >> 6, c = lin & 63;
        tile[r][c] = src[((size_t)(ge * 256 + k0 + r)) * 256 + d0 + c];
    }
    __syncthreads();
#pragma unroll
    for (int j = 0; j < 16; ++j) {
        int lin = j * 256 + t;
        int r = lin >> 6, c = lin & 63;     // r = d offset, c = k offset
        int d = d0 + r;
        int row = ilv ? (d * NG + g) : (g * 256 + d);
        dst[((size_t)(e * NG * 256 + row)) * K_ + k0 + c] = (__bf16)tile[c][r];
    }
}

// ---------------- gemm1: r15 MODE0 (f32 reg-staged, fused scan1, deferred epi) ----------------
__global__ __launch_bounds__(512, 1) void gemm1_k(const float* __restrict__ Af,
                                                  const __bf16* __restrict__ Wt,
                                                  const float* __restrict__ bias,
                                                  const float* __restrict__ rs,
                                                  __bf16* __restrict__ gout,
                                                  const float* __restrict__ hidden,
                                                  float* __restrict__ hidout) {
    constexpr int NT  = 4;               // n-panels of 128 over 512 cols
    constexpr int NMT = 8;
    const int tid = threadIdx.x;
    const int bid = blockIdx.x;
    const int e  = bid & 7;
    const int rr = bid >> 3;
    const int nt = rr & (NT - 1);
    const int ms = rr / NT;
    const int mt0 = ms * NMT;
    const int lane = tid & 63, wid = tid >> 6;
    const int wr = wid >> 2, wc = wid & 3;
    const int ln15 = lane & 15, ln16 = lane >> 4;

    __shared__ __align__(16) __bf16 As[2][32768];
    __shared__ float cAl[64], cBl[64];
    __shared__ float chL[2][64];

    bf16x8 Breg[2][8];
    {
        const __bf16* bp = Wt + ((size_t)e * 512 + nt * 128 + wc * 32 + ln15) * K_ + ln16 * 8;
#pragma unroll
        for (int j = 0; j < 2; ++j)
#pragma unroll
            for (int s = 0; s < 8; ++s)
                Breg[j][s] = *(const bf16x8*)(bp + (size_t)j * 16 * K_ + s * 32);
    }
    f32x4 bias_v[2];
#pragma unroll
    for (int j = 0; j < 2; ++j)
#pragma unroll
        for (int q = 0; q < 4; ++q) {
            int n = nt * 128 + wc * 32 + j * 16 + (ln16 << 2) + q;
            bias_v[j][q] = bias[((n & 1) * E_ + e) * 256 + (n >> 1)];
        }

    const int sr = tid >> 5, sr2 = sr >> 2;
    const int gg0 = (tid & 31) ^ sr2;
    const size_t Aoff = ((size_t)e * M_ + (size_t)mt0 * 128) * K_;
    const float* sEf = Af + Aoff + (size_t)sr * K_ + gg0 * 8;
    const float* sOf = Af + Aoff + (size_t)sr * K_ + (gg0 ^ 4) * 8;
    __bf16* const dbase0 = &As[0][tid * 8];
    __bf16* const dbase1 = &As[1][tid * 8];

    f32x4 tA[8], tB[8];
    auto loadx = [&](int tt) {
        const size_t toff = (size_t)tt * (128 * K_);
#pragma unroll
        for (int q = 0; q < 8; ++q) {
            const float* s = ((q & 1) ? sOf : sEf) + toff + q * (16 * K_);
            tA[q] = *(const f32x4*)s;
            tB[q] = *(const f32x4*)(s + 4);
        }
    };
    auto writex = [&](int buf) {
        __bf16* d = buf ? dbase1 : dbase0;
#pragma unroll
        for (int q = 0; q < 8; ++q) {
            bf16x8 w;
#pragma unroll
            for (int k = 0; k < 4; ++k) { w[k] = (__bf16)tA[q][k]; w[4 + k] = (__bf16)tB[q][k]; }
            *(bf16x8*)(d + q * 4096) = w;
        }
    };

    const int rowb = (wr * 64 + ln15 * 4) * K_;
    const int gb = ln16 ^ (lane & 7);
    const int pe_off = rowb + gb * 8;
    const int po_off = rowb + (gb ^ 4) * 8;

    auto compute = [&](f32x4 (&acc)[4][2], int buf) {
        const __bf16* pe = &As[0][0] + buf * 32768 + pe_off;
        const __bf16* po = &As[0][0] + buf * 32768 + po_off;
#pragma unroll
        for (int s = 0; s < 8; ++s) {
            const __bf16* p = (s & 1) ? po : pe;
            bf16x8 af[4];
#pragma unroll
            for (int i = 0; i < 4; ++i)
                af[i] = *(const bf16x8*)(p + i * K_ + (s >> 1) * 64);
#pragma unroll
            for (int i = 0; i < 4; ++i)
#pragma unroll
                for (int j = 0; j < 2; ++j)
                    acc[i][j] = __builtin_amdgcn_mfma_f32_16x16x32_bf16(Breg[j][s], af[i], acc[i][j], 0, 0, 0);
        }
    };

    auto do_epi = [&](f32x4 (&acc)[4][2], int tp, const f32x4& rs4p, const float* hidvp) {
        const bool cs = ((tp & 3) == 0);
        const int c = tp >> 2;
        const int mb = (mt0 + tp) * 128 + wr * 64 + ln15 * 4;
        f32x4 rsv;
#pragma unroll
        for (int q = 0; q < 4; ++q) rsv[q] = 1.0f - rs4p[q];
        float PA[2][2][4], PB[2][2][4], LA[2][2], LB[2][2], EA[2][2], EB[2][2];
#pragma unroll
        for (int j = 0; j < 2; ++j) {
#pragma unroll
            for (int dq = 0; dq < 2; ++dq) {
#pragma unroll
                for (int i = 0; i < 4; ++i) {
                    float uv = acc[i][j][dq * 2 + 0] + bias_v[j][dq * 2 + 0];
                    float uf = acc[i][j][dq * 2 + 1] + bias_v[j][dq * 2 + 1];
                    float f = sigm_f(uf) * rsv[i];
                    float b = (1.0f - f) * tanh_f(uv);
                    if (i == 0) { PA[j][dq][0] = f; PB[j][dq][0] = b; }
                    else { PB[j][dq][i] = __builtin_fmaf(f, PB[j][dq][i - 1], b);
                           PA[j][dq][i] = PA[j][dq][i - 1] * f; }
                }
                LA[j][dq] = PA[j][dq][3]; LB[j][dq] = PB[j][dq][3];
                lane_scan(LA[j][dq], LB[j][dq], EA[j][dq], EB[j][dq], ln15);
            }
#pragma unroll
            for (int i = 0; i < 4; ++i) acc[i][j] = f32x4{};
        }
        if (wr == 0 && ln15 == 15) {
#pragma unroll
            for (int j = 0; j < 2; ++j)
#pragma unroll
                for (int dq = 0; dq < 2; ++dq) {
                    int sl = wc * 16 + j * 8 + ln16 * 2 + dq;
                    cAl[sl] = LA[j][dq]; cBl[sl] = LB[j][dq];
                }
        }
        asm volatile("s_waitcnt lgkmcnt(0)" ::: "memory");
        __builtin_amdgcn_s_barrier();
#pragma unroll
        for (int j = 0; j < 2; ++j) {
            const int D0 = nt * 64 + wc * 16 + j * 8 + ln16 * 2;
            float h0q[2];
#pragma unroll
            for (int dq = 0; dq < 2; ++dq) {
                const int sl = wc * 16 + j * 8 + ln16 * 2 + dq;
                float hp = cs ? hidvp[j * 2 + dq] : chL[tp & 1][sl];
                float hsv = wr ? __builtin_fmaf(cAl[sl], hp, cBl[sl]) : hp;
                h0q[dq] = __builtin_fmaf(EA[j][dq], hsv, EB[j][dq]);
                if (wr == 1 && ln15 == 15) {
                    float he = __builtin_fmaf(LA[j][dq], hsv, LB[j][dq]);
                    chL[(tp + 1) & 1][sl] = he;
                    if ((tp & 3) == 3)
                        hidout[(e * 16 + ms * 2 + c) * 512 + D0 + dq] = he;
                }
            }
#pragma unroll
            for (int i = 0; i < 4; ++i) {
                float ha = __builtin_fmaf(PA[j][0][i], h0q[0], PB[j][0][i]);
                float hb = __builtin_fmaf(PA[j][1][i], h0q[1], PB[j][1][i]);
                bf16x2 pk; pk[0] = (__bf16)ha; pk[1] = (__bf16)hb;
                *(unsigned int*)&gout[((size_t)e * M_ + mb + i) * 256 + D0] =
                    __builtin_bit_cast(unsigned int, pk);
            }
        }
    };

    // prologue
    loadx(0);
    asm volatile("s_waitcnt vmcnt(0)" ::: "memory");
    writex(0);
    asm volatile("s_waitcnt lgkmcnt(0)" ::: "memory");
    __builtin_amdgcn_s_barrier();
    __builtin_amdgcn_sched_barrier(0);

    f32x4 accA[4][2] = {}, accB[4][2] = {};
    f32x4 rs4_p = {};
    float hidv_p[4] = {0.f, 0.f, 0.f, 0.f};
    int buf = 0;

    auto iter = [&](int t, f32x4 (&accC)[4][2], f32x4 (&accP)[4][2]) {
        const int c = t >> 2;
        f32x4 rs4_n;
        float hidv_n[4];
        {
            const int mbh = (mt0 + t) * 128 + wr * 64 + ln15 * 4;
            rs4_n = *(const f32x4*)&rs[mbh];
            const int nrow = e * 16 + ms * 2 + c;
            f32x2 ha = *(const f32x2*)&hidden[nrow * 512 + (nt * 64 + wc * 16 + 0 + ln16 * 2)];
            f32x2 hb = *(const f32x2*)&hidden[nrow * 512 + (nt * 64 + wc * 16 + 8 + ln16 * 2)];
            hidv_n[0] = ha[0]; hidv_n[1] = ha[1]; hidv_n[2] = hb[0]; hidv_n[3] = hb[1];
            __builtin_amdgcn_sched_barrier(0);
        }
        if (t + 1 < NMT) loadx(t + 1);
        __builtin_amdgcn_sched_barrier(0);
        compute(accC, buf);
        if (t > 0) do_epi(accP, t - 1, rs4_p, hidv_p);
        if (t == 0) { asm volatile("s_waitcnt vmcnt(0)" ::: "memory"); }
        else        { asm volatile("s_waitcnt vmcnt(8)" ::: "memory"); }
        if (t + 1 < NMT) writex(buf ^ 1);
        asm volatile("s_waitcnt lgkmcnt(0)" ::: "memory");
        __builtin_amdgcn_s_barrier();
        __builtin_amdgcn_sched_barrier(0);
        buf ^= 1;
        rs4_p = rs4_n;
#pragma unroll
        for (int q = 0; q < 4; ++q) hidv_p[q] = hidv_n[q];
    };

#pragma unroll 1
    for (int t2 = 0; t2 < NMT; t2 += 2) {
        iter(t2, accA, accB);
        iter(t2 + 1, accB, accA);
    }
    do_epi(accB, NMT - 1, rs4_p, hidv_p);
}

// ---------------- gemm2: BK=128 chunked dbuf (64KB LDS, 2 blocks/CU), fused scan2 ----------------
__global__ __launch_bounds__(512, 4) void gemm2_k(const __bf16* __restrict__ A,
                                                  const __bf16* __restrict__ Wt,
                                                  const float* __restrict__ bias,
                                                  const float* __restrict__ rs,
                                                  __bf16* __restrict__ gout,
                                                  const float* __restrict__ hidden,
                                                  float* __restrict__ hidout) {
    constexpr int NMT = 8;               // m-tiles per block (grid = 512)
    const int tid = threadIdx.x;
    const int bid = blockIdx.x;          // 512 blocks, bid&7 = e = XCD
    const int e  = bid & 7;
    const int rr = bid >> 3;             // 0..63
    const int nt = rr & 7;               // 8 n-panels of 128 over 1024 cols
    const int ms = rr >> 3;              // 0..7
    const int mt0 = ms * NMT;
    const int lane = tid & 63, wid = tid >> 6;
    const int wr = wid >> 2, wc = wid & 3;          // 2x4 wave grid
    const int ln15 = lane & 15, ln16 = lane >> 4;

    __shared__ __align__(16) __bf16 As[2][16384];   // 2 chunks x (128 rows x 128 k) = 64 KB
    __shared__ float cAl[32], cBl[32];
    __shared__ float chL[2][32];

    // ---- B panel into registers ----
    bf16x8 Breg[2][8];
    {
        const __bf16* bp = Wt + ((size_t)e * 1024 + nt * 128 + wc * 32 + ln15) * K_ + ln16 * 8;
#pragma unroll
        for (int j = 0; j < 2; ++j)
#pragma unroll
            for (int s = 0; s < 8; ++s)
                Breg[j][s] = *(const bf16x8*)(bp + (size_t)j * 16 * K_ + s * 32);
    }
    f32x4 bias_v[2];
#pragma unroll
    for (int j = 0; j < 2; ++j)
#pragma unroll
        for (int q = 0; q < 4; ++q) {
            int n = nt * 128 + wc * 32 + j * 16 + (ln16 << 2) + q;
            bias_v[j][q] = bias[((n & 3) * E_ + e) * 256 + (n >> 2)];
        }

    // ---- staging: chunk = 128 rows x 128 k; 4 glds/thread; key=(row>>2)&7 = (tr>>2)&7 ----
    const size_t Ae = ((size_t)e * M_ + (size_t)mt0 * 128) * K_;
    const int tr = tid >> 4;             // 0..31
    const int g16 = tid & 15;
    const int tr2 = (tr >> 2) & 7;
    const __bf16* sA = A + Ae + (size_t)tr * K_ + ((g16 ^ tr2) * 8);
    __bf16* const db0 = &As[0][tid * 8];
    __bf16* const db1 = &As[1][tid * 8];

    auto stage = [&](int tt, int kc, int buf) {
        const __bf16* s = sA + (size_t)tt * (128 * K_) + kc * 128;
        __bf16* d = buf ? db1 : db0;
#pragma unroll
        for (int q = 0; q < 4; ++q)
            g2lds16(s + (size_t)q * (32 * K_), d + q * 4096);
    };

    // ---- ds_read bases (chunk row stride 128 elements) ----
    const int rowb = (wr * 64 + ln15 * 4) * 128;
    const int kb = (ln15 >> 2) & 1;
    const int g3 = (ln16 ^ (ln15 & 3)) * 8;
    const int pe_off = rowb + kb * 32 + g3;
    const int po_off = rowb + (32 - kb * 32) + g3;

    auto compute = [&](f32x4 (&acc)[4][2], int buf, int kc) {
        const __bf16* pe = &As[0][0] + buf * 16384 + pe_off;
        const __bf16* po = &As[0][0] + buf * 16384 + po_off;
#pragma unroll
        for (int s = 0; s < 4; ++s) {
            const __bf16* p = ((s & 1) ? po : pe) + (s >> 1) * 64;
            bf16x8 af[4];
#pragma unroll
            for (int i = 0; i < 4; ++i)
                af[i] = *(const bf16x8*)(p + i * 128);
#pragma unroll
            for (int i = 0; i < 4; ++i)
#pragma unroll
                for (int j = 0; j < 2; ++j)
                    acc[i][j] = __builtin_amdgcn_mfma_f32_16x16x32_bf16(Breg[j][kc * 4 + s], af[i], acc[i][j], 0, 0, 0);
        }
    };

    auto do_epi = [&](f32x4 (&acc)[4][2], int tp, const f32x4& rs4p, const float* hidvp) {
        const bool cs = ((tp & 3) == 0);
        const int c = tp >> 2;
        const int mb = (mt0 + tp) * 128 + wr * 64 + ln15 * 4;
        const int nrow = e * 16 + ms * 2 + c;
        f32x4 rsv;
#pragma unroll
        for (int q = 0; q < 4; ++q) rsv[q] = 1.0f - rs4p[q];
        float PA[2][4], PB[2][4], Ov[2][4], LA[2], LB[2], EA[2], EB[2];
#pragma unroll
        for (int j = 0; j < 2; ++j) {
#pragma unroll
            for (int i = 0; i < 4; ++i) {
                float f  = sigm_f(acc[i][j][0] + bias_v[j][0]) * rsv[i];
                float iv = sigm_f(acc[i][j][1] + bias_v[j][1]);
                float o  = sigm_f(acc[i][j][2] + bias_v[j][2]);
                float z  = tanh_f(acc[i][j][3] + bias_v[j][3]);
                float b  = (1.0f - f) * iv * z;
                Ov[j][i] = o;
                if (i == 0) { PA[j][0] = f; PB[j][0] = b; }
                else { PB[j][i] = __builtin_fmaf(f, PB[j][i - 1], b); PA[j][i] = PA[j][i - 1] * f; }
                acc[i][j] = f32x4{};
            }
            LA[j] = PA[j][3]; LB[j] = PB[j][3];
            lane_scan(LA[j], LB[j], EA[j], EB[j], ln15);
        }
        if (wr == 0 && ln15 == 15) {
#pragma unroll
            for (int j = 0; j < 2; ++j) {
                int sl = wc * 8 + j * 4 + ln16;
                cAl[sl] = LA[j]; cBl[sl] = LB[j];
            }
        }
        asm volatile("s_waitcnt lgkmcnt(0)" ::: "memory");
        __builtin_amdgcn_s_barrier();
#pragma unroll
        for (int j = 0; j < 2; ++j) {
            const int sl = wc * 8 + j * 4 + ln16;
            const int d = nt * 32 + sl;
            float hp = cs ? hidvp[j] : chL[tp & 1][sl];
            float hsv = wr ? __builtin_fmaf(cAl[sl], hp, cBl[sl]) : hp;
            float h0 = __builtin_fmaf(EA[j], hsv, EB[j]);
#pragma unroll
            for (int i = 0; i < 4; ++i) {
                float h = __builtin_fmaf(PA[j][i], h0, PB[j][i]);
                gout[((size_t)e * M_ + mb + i) * 256 + d] = (__bf16)(h * Ov[j][i]);
            }
            if (wr == 1 && ln15 == 15) {
                float he = __builtin_fmaf(LA[j], hsv, LB[j]);
                chL[(tp + 1) & 1][sl] = he;
                if ((tp & 3) == 3)
                    hidout[nrow * 512 + 256 + d] = he;
            }
        }
    };

    // ---- prologue: chunk(0,0) -> buf0 ----
    stage(0, 0, 0);
    asm volatile("s_waitcnt vmcnt(0)" ::: "memory");
    __builtin_amdgcn_s_barrier();
    __builtin_amdgcn_sched_barrier(0);

    f32x4 accA[4][2] = {}, accB[4][2] = {};
    f32x4 rs4_p = {};
    float hidv_p[2] = {0.f, 0.f};

    auto iter = [&](int t, f32x4 (&accC)[4][2], f32x4 (&accP)[4][2]) {
        // ---- hoisted loads for tile t (consumed by epilogue at iter t+1) ----
        f32x4 rs4_n;
        float hidv_n[2];
        {
            const int mbh = (mt0 + t) * 128 + wr * 64 + ln15 * 4;
            rs4_n = *(const f32x4*)&rs[mbh];
            const int nrow = e * 16 + ms * 2 + (t >> 2);
            hidv_n[0] = hidden[nrow * 512 + 256 + (nt * 32 + wc * 8 + 0 + ln16)];
            hidv_n[1] = hidden[nrow * 512 + 256 + (nt * 32 + wc * 8 + 4 + ln16)];
            __builtin_amdgcn_sched_barrier(0);
        }
        const bool pf = (t + 1 < NMT);
        stage(t, 1, 1);                         // chunk t.1 -> buf1
        compute(accC, 0, 0);                    // chunk t.0 (buf0)
        __builtin_amdgcn_s_barrier();           // buf0 consumed
        if (pf) stage(t + 1, 0, 0);             // chunk t+1.0 -> buf0
        if (t > 0) do_epi(accP, t - 1, rs4_p, hidv_p);
        // wait chunk t.1: newer = pf-stage(4) + epi stores(8)
        if (t == 0)      { asm volatile("s_waitcnt vmcnt(4)" ::: "memory"); }
        else if (pf)     { asm volatile("s_waitcnt vmcnt(12)" ::: "memory"); }
        else             { asm volatile("s_waitcnt vmcnt(8)" ::: "memory"); }
        __builtin_amdgcn_s_barrier();
        compute(accC, 1, 1);                    // chunk t.1 (buf1)
        // wait chunk t+1.0 before next tile: newer = epi stores(8) (t>0)
        if (pf) {
            if (t > 0) { asm volatile("s_waitcnt vmcnt(8)" ::: "memory"); }
            else       { asm volatile("s_waitcnt vmcnt(0)" ::: "memory"); }
        }
        __builtin_amdgcn_s_barrier();           // buf1 free for next stage
        __builtin_amdgcn_sched_barrier(0);
        rs4_p = rs4_n;
        hidv_p[0] = hidv_n[0]; hidv_p[1] = hidv_n[1];
    };

#pragma unroll 1
    for (int t2 = 0; t2 < NMT; t2 += 2) {
        iter(t2, accA, accB);
        iter(t2 + 1, accB, accA);
    }
    do_epi(accB, NMT - 1, rs4_p, hidv_p);
}

// ---------------- gemm3: r15 MODE2 (LDS-staged, plain linear+bias -> f32) ----------------
__global__ __launch_bounds__(512, 1) void gemm3_k(const __bf16* __restrict__ A,
                                                  const __bf16* __restrict__ Wt,
                                                  const float* __restrict__ bias,
                                                  float* __restrict__ fout) {
    constexpr int NT  = 2;
    constexpr int NMT = 4;
    const int tid = threadIdx.x;
    const int bid = blockIdx.x;
    const int e  = bid & 7;
    const int rr = bid >> 3;
    const int nt = rr & (NT - 1);
    const int ms = rr / NT;
    const int mt0 = ms * NMT;
    const int lane = tid & 63, wid = tid >> 6;
    const int wr = wid >> 2, wc = wid & 3;
    const int ln15 = lane & 15, ln16 = lane >> 4;

    __shared__ __align__(16) __bf16 As[2][32768];

    bf16x8 Breg[2][8];
    {
        const __bf16* bp = Wt + ((size_t)e * 256 + nt * 128 + wc * 32 + ln15) * K_ + ln16 * 8;
#pragma unroll
        for (int j = 0; j < 2; ++j)
#pragma unroll
            for (int s = 0; s < 8; ++s)
                Breg[j][s] = *(const bf16x8*)(bp + (size_t)j * 16 * K_ + s * 32);
    }
    f32x4 bias_v[2];
#pragma unroll
    for (int j = 0; j < 2; ++j)
        bias_v[j] = *(const f32x4*)&bias[e * 256 + nt * 128 + wc * 32 + j * 16 + (ln16 << 2)];

    const int sr = tid >> 5, sr2 = sr >> 2;
    const int gg0 = (tid & 31) ^ sr2;
    const size_t Aoff = ((size_t)e * M_ + (size_t)mt0 * 128) * K_;
    const __bf16* sE = A + Aoff + (size_t)sr * K_ + gg0 * 8;
    const __bf16* sO = A + Aoff + (size_t)sr * K_ + (gg0 ^ 4) * 8;
    __bf16* const dbase0 = &As[0][tid * 8];
    __bf16* const dbase1 = &As[1][tid * 8];

    auto stage = [&](int tt, int buf) {
        __bf16* d = buf ? dbase1 : dbase0;
        const size_t toff = (size_t)tt * (128 * K_);
#pragma unroll
        for (int q = 0; q < 8; ++q)
            g2lds16(((q & 1) ? sO : sE) + toff + q * (16 * K_), d + q * 4096);
    };

    const int rowb = (wr * 64 + ln15 * 4) * K_;
    const int gb = ln16 ^ (lane & 7);
    const int pe_off = rowb + gb * 8;
    const int po_off = rowb + (gb ^ 4) * 8;

    f32x4 acc[4][2] = {};
    auto compute = [&](int buf) {
        const __bf16* pe = &As[0][0] + buf * 32768 + pe_off;
        const __bf16* po = &As[0][0] + buf * 32768 + po_off;
#pragma unroll
        for (int s = 0; s < 8; ++s) {
            const __bf16* p = (s & 1) ? po : pe;
            bf16x8 af[4];
#pragma unroll
            for (int i = 0; i < 4; ++i)
                af[i] = *(const bf16x8*)(p + i * K_ + (s >> 1) * 64);
#pragma unroll
            for (int i = 0; i < 4; ++i)
#pragma unroll
                for (int j = 0; j < 2; ++j)
                    acc[i][j] = __builtin_amdgcn_mfma_f32_16x16x32_bf16(Breg[j][s], af[i], acc[i][j], 0, 0, 0);
        }
    };

    stage(0, 0);
    asm volatile("s_waitcnt vmcnt(0)" ::: "memory");
    __builtin_amdgcn_s_barrier();
    __builtin_amdgcn_sched_barrier(0);

    int buf = 0;
    for (int t = 0; t < NMT; ++t) {
        if (t + 1 < NMT) stage(t + 1, buf ^ 1);
        compute(buf);
        const int mb = (mt0 + t) * 128 + wr * 64 + ln15 * 4;
#pragma unroll
        for (int j = 0; j < 2; ++j) {
            const int n0 = nt * 128 + wc * 32 + j * 16 + (ln16 << 2);
#pragma unroll
            for (int i = 0; i < 4; ++i) {
                f32x4 o = acc[i][j] + bias_v[j];
                *(f32x4*)&fout[((size_t)e * M_ + mb + i) * 256 + n0] = o;
                acc[i][j] = f32x4{};
            }
        }
        asm volatile("s_waitcnt vmcnt(8) lgkmcnt(0)" ::: "memory");
        __builtin_amdgcn_s_barrier();
        __builtin_amdgcn_sched_barrier(0);
        buf ^= 1;
    }
}

extern "C" void kernel_launch(void* const* d_in, const int* in_sizes, int n_in,
                              void* d_out, int out_size, void* d_ws, size_t ws_size,
                              hipStream_t stream) {
    const float* x      = (const float*)d_in[0];
    const float* hidden = (const float*)d_in[1];
    const float* rs     = (const float*)d_in[2];
    const float* W_in   = (const float*)d_in[3];
    const float* b_in   = (const float*)d_in[4];
    const float* W_mid  = (const float*)d_in[5];
    const float* b_mid  = (const float*)d_in[6];
    const float* W_out  = (const float*)d_in[7];
    const float* b_out  = (const float*)d_in[8];
    float* out = (float*)d_out;

    char* ws = (char*)d_ws;
    const size_t MiB = (size_t)1 << 20;
    __bf16* Wt1 = (__bf16*)(ws + 0);               // 2 MiB  (ilv d*2+g)
    __bf16* Wt2 = (__bf16*)(ws + 2 * MiB);         // 4 MiB  (ilv d*4+g)
    __bf16* Wt3 = (__bf16*)(ws + 6 * MiB);         // 1 MiB  (plain)
    __bf16* v4b = (__bf16*)(ws + 8 * MiB);         // 32 MiB scan1 output
    __bf16* G   = (__bf16*)(ws + 72 * MiB);        // 32 MiB scan2 output

    float* hidout = out + (size_t)E_ * M_ * 256;

    transw_all<<<dim3(4, 4, 56), 256, 0, stream>>>(W_in, W_mid, W_out, Wt1, Wt2, Wt3);

    gemm1_k<<<256, 512, 0, stream>>>(x, Wt1, b_in, rs, v4b, hidden, hidout);
    gemm2_k<<<512, 512, 0, stream>>>(v4b, Wt2, b_mid, rs, G, hidden, hidout);
    gemm3_k<<<256, 512, 0, stream>>>(G, Wt3, b_out, out);
}